// Round 6
// baseline (31.321 us; speedup 1.0000x reference)
//
#include <hip/hip_runtime.h>

#define EPSF 1e-4f

typedef float f32x4 __attribute__((ext_vector_type(4)));
typedef float f32x2 __attribute__((ext_vector_type(2)));

// Fast per-2x2-block computation (see R1 notes): v_rcp_f32 for shared
// divisors, native v_exp_f32, FMA contraction allowed, reference summation
// order preserved. absmax 0.0078 vs threshold 0.058.
__device__ __forceinline__ float fuzzy_one(float v0, float v1, float v2, float v3) {
    float k0 = (v1 + v2) * 0.5f;
    float k1 = (((v0 + v1) + v2) + v3) * 0.25f;
    float vavg = (k0 + k1) * 0.5f;

    float o0 = fabsf(v0 - vavg);
    float o1 = fabsf(v1 - vavg);
    float o2 = fabsf(v2 - vavg);
    float o3 = fabsf(v3 - vavg);
    float sg0 = (o1 + o2) * 0.5f + EPSF;
    float sg1 = (((o0 + o1) + o2) + o3) * 0.25f + EPSF;

    float rs0 = __builtin_amdgcn_rcpf(sg0);
    float rs1 = __builtin_amdgcn_rcpf(sg1);
    float c0 = -0.5f * rs0 * rs0;
    float c1 = -0.5f * rs1 * rs1;

    float dv00 = v0 - k0, dv01 = v1 - k0, dv02 = v2 - k0, dv03 = v3 - k0;
    float dv10 = v0 - k1, dv11 = v1 - k1, dv12 = v2 - k1, dv13 = v3 - k1;

    float p00 = __expf(dv00 * dv00 * c0);
    float p01 = __expf(dv01 * dv01 * c0);
    float p02 = __expf(dv02 * dv02 * c0);
    float p03 = __expf(dv03 * dv03 * c0);
    float p10 = __expf(dv10 * dv10 * c1);
    float p11 = __expf(dv11 * dv11 * c1);
    float p12 = __expf(dv12 * dv12 * c1);
    float p13 = __expf(dv13 * dv13 * c1);

    float a0 = (p00 + p10) * 0.5f;
    float a1 = (p01 + p11) * 0.5f;
    float a2 = (p02 + p12) * 0.5f;
    float a3 = (p03 + p13) * 0.5f;
    float pm0 = fmaxf(p00, p10);
    float pm1 = fmaxf(p01, p11);
    float pm2 = fmaxf(p02, p12);
    float pm3 = fmaxf(p03, p13);
    float thresh = fminf(fminf(fminf(pm0, pm1), pm2), pm3);

    bool primary = (a1 >= thresh);
    bool s_cond  = (sg1 < 0.001f);

    float num = ((a0 * v0 + a1 * v1) + a2 * v2) + a3 * v3;
    float den = ((a0 + a1) + a2) + a3;
    float denoised = num * __builtin_amdgcn_rcpf(den);

    return primary ? k1 : (s_cond ? vavg : denoised);
}

// x: (512, 256, 256) f32 flat; out: (512, 128, 128) f32.
// R1 layout (best measured: 29.7us): thread = one float4 from row 2i + one
// from row 2i+1 -> two outputs, all lane-contiguous. R2/R3 MLP widenings
// both regressed => BW-saturated, not latency-limited.
// This round: nontemporal (nt) hints via clang ext_vector types (HIP float4
// structs are rejected by the builtin).
__global__ void __launch_bounds__(256) fuzzy_kernel(const float* __restrict__ x,
                                                    float* __restrict__ out) {
    unsigned t = blockIdx.x * 256u + threadIdx.x;     // 0 .. 4194303
    unsigned jp = t & 63u;                             // float4 index within row
    unsigned i  = (t >> 6) & 127u;                     // output row
    unsigned bc = t >> 13;                             // channel (512)

    const f32x4* top = reinterpret_cast<const f32x4*>(
        x + (size_t)bc * 65536u + (size_t)(2u * i) * 256u) + jp;
    const f32x4* bot = top + 64;                       // next input row
    f32x4 a = __builtin_nontemporal_load(top);
    f32x4 b = __builtin_nontemporal_load(bot);

    float r0 = fuzzy_one(a.x, a.y, b.x, b.y);
    float r1 = fuzzy_one(a.z, a.w, b.z, b.w);

    f32x2 r = {r0, r1};
    f32x2* o = reinterpret_cast<f32x2*>(
        out + (size_t)bc * 16384u + (size_t)i * 128u) + jp;
    __builtin_nontemporal_store(r, o);
}

extern "C" void kernel_launch(void* const* d_in, const int* in_sizes, int n_in,
                              void* d_out, int out_size, void* d_ws, size_t ws_size,
                              hipStream_t stream) {
    const float* x = (const float*)d_in[0];
    float* out = (float*)d_out;
    dim3 grid(16384), block(256);
    hipLaunchKernelGGL(fuzzy_kernel, grid, block, 0, stream, x, out);
}

// Round 8
// 29.757 us; speedup vs baseline: 1.0526x; 1.0526x over previous
//
#include <hip/hip_runtime.h>

#define EPSF 1e-4f

// Fast per-2x2-block computation: v_rcp_f32 for the 3 shared divisors,
// native v_exp_f32 (__expf), FMA contraction allowed, reference summation
// order preserved. absmax 0.0078 vs threshold 0.058.
__device__ __forceinline__ float fuzzy_one(float v0, float v1, float v2, float v3) {
    float k0 = (v1 + v2) * 0.5f;
    float k1 = (((v0 + v1) + v2) + v3) * 0.25f;
    float vavg = (k0 + k1) * 0.5f;

    float o0 = fabsf(v0 - vavg);
    float o1 = fabsf(v1 - vavg);
    float o2 = fabsf(v2 - vavg);
    float o3 = fabsf(v3 - vavg);
    float sg0 = (o1 + o2) * 0.5f + EPSF;
    float sg1 = (((o0 + o1) + o2) + o3) * 0.25f + EPSF;

    float rs0 = __builtin_amdgcn_rcpf(sg0);
    float rs1 = __builtin_amdgcn_rcpf(sg1);
    float c0 = -0.5f * rs0 * rs0;
    float c1 = -0.5f * rs1 * rs1;

    float dv00 = v0 - k0, dv01 = v1 - k0, dv02 = v2 - k0, dv03 = v3 - k0;
    float dv10 = v0 - k1, dv11 = v1 - k1, dv12 = v2 - k1, dv13 = v3 - k1;

    float p00 = __expf(dv00 * dv00 * c0);
    float p01 = __expf(dv01 * dv01 * c0);
    float p02 = __expf(dv02 * dv02 * c0);
    float p03 = __expf(dv03 * dv03 * c0);
    float p10 = __expf(dv10 * dv10 * c1);
    float p11 = __expf(dv11 * dv11 * c1);
    float p12 = __expf(dv12 * dv12 * c1);
    float p13 = __expf(dv13 * dv13 * c1);

    float a0 = (p00 + p10) * 0.5f;
    float a1 = (p01 + p11) * 0.5f;
    float a2 = (p02 + p12) * 0.5f;
    float a3 = (p03 + p13) * 0.5f;
    float pm0 = fmaxf(p00, p10);
    float pm1 = fmaxf(p01, p11);
    float pm2 = fmaxf(p02, p12);
    float pm3 = fmaxf(p03, p13);
    float thresh = fminf(fminf(fminf(pm0, pm1), pm2), pm3);

    bool primary = (a1 >= thresh);
    bool s_cond  = (sg1 < 0.001f);

    float num = ((a0 * v0 + a1 * v1) + a2 * v2) + a3 * v3;
    float den = ((a0 + a1) + a2) + a3;
    float denoised = num * __builtin_amdgcn_rcpf(den);

    return primary ? k1 : (s_cond ? vavg : denoised);
}

// x: (512, 256, 256) f32 flat; out: (512, 128, 128) f32.
// BEST CONFIG (R1, 29.7us = 90% of achievable HBM BW on this 4:1 stream):
// thread = one float4 from row 2i + one from row 2i+1 -> two outputs.
// Lane-contiguous loads (1KB/wave/instr). Measured dead ends: stride-2
// lanes (R2 31.2), 2 row-pairs/thread (R3 31.0), nt hints (R5 31.3).
// R6 post-timing divergence with this exact source + exact first-pass
// absmax/timing => transient, kernel is deterministic by construction.
__global__ void __launch_bounds__(256) fuzzy_kernel(const float* __restrict__ x,
                                                    float* __restrict__ out) {
    unsigned t = blockIdx.x * 256u + threadIdx.x;     // 0 .. 4194303
    unsigned jp = t & 63u;                             // float4 index within row
    unsigned i  = (t >> 6) & 127u;                     // output row
    unsigned bc = t >> 13;                             // channel (512)

    const float4* top = reinterpret_cast<const float4*>(
        x + (size_t)bc * 65536u + (size_t)(2u * i) * 256u) + jp;
    const float4* bot = top + 64;                      // next input row
    float4 a = *top;
    float4 b = *bot;

    float r0 = fuzzy_one(a.x, a.y, b.x, b.y);
    float r1 = fuzzy_one(a.z, a.w, b.z, b.w);

    float2* o = reinterpret_cast<float2*>(
        out + (size_t)bc * 16384u + (size_t)i * 128u) + jp;
    *o = make_float2(r0, r1);
}

extern "C" void kernel_launch(void* const* d_in, const int* in_sizes, int n_in,
                              void* d_out, int out_size, void* d_ws, size_t ws_size,
                              hipStream_t stream) {
    const float* x = (const float*)d_in[0];
    float* out = (float*)d_out;
    dim3 grid(16384), block(256);
    hipLaunchKernelGGL(fuzzy_kernel, grid, block, 0, stream, x, out);
}